// Round 1
// baseline (611.509 us; speedup 1.0000x reference)
//
#include <hip/hip_runtime.h>
#include <math.h>

#define D_MODEL 1024
#define N_HEADS 16
#define D_K 64
#define B_SZ 64
#define S_LEN 2048

// ---------------- kernel 0: qh[b,n] = q[b,:] @ Wq[:,n] + bq[n] ----------------
// grid 256 = (64 b x 4 n-chunks), block 256. q row read via uniform scalar loads.
__global__ __launch_bounds__(256) void k_qh(const float* __restrict__ q,
                                            const float* __restrict__ Wq,
                                            const float* __restrict__ bq,
                                            float* __restrict__ qh) {
    int b = blockIdx.x >> 2;
    int nc = blockIdx.x & 3;
    int t = threadIdx.x;
    int n = nc * 256 + t;
    const float* w = Wq + n;
    const float* qb = q + (size_t)b * D_MODEL;   // uniform address -> s_load
    float acc = 0.f;
#pragma unroll 8
    for (int d = 0; d < D_MODEL; ++d) acc = fmaf(qb[d], w[(size_t)d * D_MODEL], acc);
    qh[(size_t)b * D_MODEL + n] = acc + bq[n];
}

// ---------------- kernel 1: qt[b,h,d] = (1/8) * sum_j qh[b,h*64+j] * Wk[d, h*64+j] ----------------
// grid 1024 = (b,h), block 256; qh slice via uniform scalar loads (no LDS, no barrier)
__global__ __launch_bounds__(256) void k_qtil(const float* __restrict__ qh,
                                              const float* __restrict__ Wk,
                                              float* __restrict__ qt) {
    int b = blockIdx.x >> 4;
    int h = blockIdx.x & 15;
    int t = threadIdx.x;
    const float* qhb = qh + (size_t)b * D_MODEL + h * D_K;  // uniform -> s_load
#pragma unroll
    for (int p = 0; p < 4; ++p) {
        int d = p * 256 + t;
        const float* w = Wk + (size_t)d * D_MODEL + h * D_K;
        float acc = 0.f;
#pragma unroll
        for (int j4 = 0; j4 < 16; ++j4) {
            float4 w4 = ((const float4*)w)[j4];
            float4 q4 = ((const float4*)qhb)[j4];   // loop-invariant uniform
            acc += w4.x * q4.x + w4.y * q4.y + w4.z * q4.z + w4.w * q4.w;
        }
        qt[((size_t)(b * N_HEADS + h)) * D_MODEL + d] = acc * 0.125f;
    }
}

// ---------------- kernel 2: scores[b,h,s] = k[b,s,:] . qt[b,h,:] ----------------
// grid 1024 = (64 b x 16 s-tiles of 128), block 256 = 4 waves.
// wave w -> heads 8*(w&1)..+7, rows 64*(w>>1)+lane. qt via uniform scalar loads (SGPR).
// k tile double-buffered in LDS (1 barrier/iter) with register-staged prefetch.
#define ST 128
#define DC 32
#define KROW 36            // 32 + 4 pad: conflict-free b128 reads (quad = 9*row % 8)
#define KTSZ (ST * KROW)   // 4608 floats per buffer
__global__ __launch_bounds__(256) void k_scores(const float* __restrict__ k,
                                                const float* __restrict__ qt,
                                                float* __restrict__ sc) {
    __shared__ float kt[2 * KTSZ];  // 36.9 KB -> 4 blocks/CU
    int b = blockIdx.x >> 4;
    int st = blockIdx.x & 15;
    int t = threadIdx.x;
    int w = __builtin_amdgcn_readfirstlane(t >> 6);  // wave id, provably uniform
    int lane = t & 63;
    int hq = (w & 1) * 8;    // head-group base (uniform)
    int sq = (w >> 1) * 64;  // s-offset within tile (uniform)
    int s0 = st * ST;
    const float* kbase = k + ((size_t)b * S_LEN + s0) * D_MODEL;
    const float* qw = qt + ((size_t)b * N_HEADS + hq) * D_MODEL;  // uniform base
    int ss = t >> 3, sd = t & 7;  // staging row/col4: idx = t + 256p -> row ss+32p
    // prologue: preload k tile for dc=0 into registers
    float4 kr[4];
#pragma unroll
    for (int p = 0; p < 4; ++p)
        kr[p] = *(const float4*)(kbase + (size_t)(ss + 32 * p) * D_MODEL + 4 * sd);
    float acc[8] = {};
    int buf = 0;
    for (int dc = 0; dc < D_MODEL; dc += DC, buf ^= 1) {
        float* ktw = kt + buf * KTSZ;
#pragma unroll
        for (int p = 0; p < 4; ++p)
            *(float4*)(ktw + (ss + 32 * p) * KROW + 4 * sd) = kr[p];
        __syncthreads();  // writes of buf visible; prev compute on buf done 2 iters ago
        int dcn = dc + DC;
        if (dcn < D_MODEL) {  // issue next-tile loads; latency hides under compute
#pragma unroll
            for (int p = 0; p < 4; ++p)
                kr[p] = *(const float4*)(kbase + (size_t)(ss + 32 * p) * D_MODEL + dcn + 4 * sd);
        }
        const float* ktr = kt + buf * KTSZ + (size_t)(sq + lane) * KROW;
#pragma unroll
        for (int d4 = 0; d4 < DC / 4; ++d4) {
            float4 kv = *(const float4*)(ktr + 4 * d4);  // only lane-varying LDS read
#pragma unroll
            for (int j = 0; j < 8; ++j) {
                float4 qv = *(const float4*)(qw + (size_t)j * D_MODEL + dc + 4 * d4);  // s_load
                acc[j] = fmaf(kv.x, qv.x, fmaf(kv.y, qv.y,
                         fmaf(kv.z, qv.z, fmaf(kv.w, qv.w, acc[j]))));
            }
        }
        // no second barrier: next iter writes the other buffer (race-free by induction)
    }
#pragma unroll
    for (int j = 0; j < 8; ++j)
        sc[((size_t)(b * N_HEADS + hq + j)) * S_LEN + s0 + sq + lane] = acc[j];
}

// ---------------- kernel 3: softmax in-place over s (row = b*16+h) ----------------
__global__ __launch_bounds__(256) void k_softmax(float* __restrict__ sc) {
    int row = blockIdx.x;
    int t = threadIdx.x;
    float4* p = (float4*)(sc + (size_t)row * S_LEN);
    float4 x0 = p[t];
    float4 x1 = p[t + 256];
    float m = fmaxf(fmaxf(fmaxf(x0.x, x0.y), fmaxf(x0.z, x0.w)),
                    fmaxf(fmaxf(x1.x, x1.y), fmaxf(x1.z, x1.w)));
#pragma unroll
    for (int o = 32; o; o >>= 1) m = fmaxf(m, __shfl_xor(m, o, 64));
    __shared__ float redm[4], reds[4];
    int w = t >> 6, lane = t & 63;
    if (lane == 0) redm[w] = m;
    __syncthreads();
    m = fmaxf(fmaxf(redm[0], redm[1]), fmaxf(redm[2], redm[3]));
    x0.x = __expf(x0.x - m); x0.y = __expf(x0.y - m);
    x0.z = __expf(x0.z - m); x0.w = __expf(x0.w - m);
    x1.x = __expf(x1.x - m); x1.y = __expf(x1.y - m);
    x1.z = __expf(x1.z - m); x1.w = __expf(x1.w - m);
    float s = x0.x + x0.y + x0.z + x0.w + x1.x + x1.y + x1.z + x1.w;
#pragma unroll
    for (int o = 32; o; o >>= 1) s += __shfl_xor(s, o, 64);
    if (lane == 0) reds[w] = s;
    __syncthreads();
    s = reds[0] + reds[1] + reds[2] + reds[3];
    float inv = 1.0f / s;
    x0.x *= inv; x0.y *= inv; x0.z *= inv; x0.w *= inv;
    x1.x *= inv; x1.y *= inv; x1.z *= inv; x1.w *= inv;
    p[t] = x0;
    p[t + 256] = x1;
}

// ---------------- kernel 4: part[ch,b,h,d] = sum_{s in chunk} attn[b,h,s] * v[b,s,d] ----------------
// grid 1024 = (64 b x 8 s-chunks x 2 d-halves), block 256; thread owns d-float2.
// attn weights via uniform scalar loads (no LDS, no barriers); v prefetched 1 iter ahead.
__global__ __launch_bounds__(256) void k_av(const float* __restrict__ v,
                                            const float* __restrict__ sc,
                                            float* __restrict__ part) {
    int b = blockIdx.x >> 4;
    int ch = (blockIdx.x >> 1) & 7;
    int dh = blockIdx.x & 1;
    int t = threadIdx.x;
    int s0 = ch * 256;
    const float* scb = sc + (size_t)b * N_HEADS * S_LEN + s0;  // uniform -> s_load
    const float* vbase = v + ((size_t)b * S_LEN + s0) * D_MODEL + dh * 512 + 2 * t;
    float2 acc[N_HEADS];
#pragma unroll
    for (int h = 0; h < N_HEADS; ++h) acc[h] = make_float2(0.f, 0.f);
    float2 c0 = *(const float2*)(vbase);
    float2 c1 = *(const float2*)(vbase + D_MODEL);
    float2 c2 = *(const float2*)(vbase + 2 * D_MODEL);
    float2 c3 = *(const float2*)(vbase + 3 * D_MODEL);
    for (int sg = 0; sg < 64; ++sg) {
        const float* np = vbase + (size_t)(4 * ((sg + 1) & 63)) * D_MODEL;  // wrap: last iter reloads row 0 (L1 hit)
        float2 n0 = *(const float2*)(np);
        float2 n1 = *(const float2*)(np + D_MODEL);
        float2 n2 = *(const float2*)(np + 2 * D_MODEL);
        float2 n3 = *(const float2*)(np + 3 * D_MODEL);
#pragma unroll
        for (int h = 0; h < N_HEADS; ++h) {
            float4 a4 = *(const float4*)(scb + (size_t)h * S_LEN + 4 * sg);  // s_load_dwordx4
            acc[h].x = fmaf(a4.x, c0.x, fmaf(a4.y, c1.x, fmaf(a4.z, c2.x, fmaf(a4.w, c3.x, acc[h].x))));
            acc[h].y = fmaf(a4.x, c0.y, fmaf(a4.y, c1.y, fmaf(a4.z, c2.y, fmaf(a4.w, c3.y, acc[h].y))));
        }
        c0 = n0; c1 = n1; c2 = n2; c3 = n3;
    }
#pragma unroll
    for (int h = 0; h < N_HEADS; ++h)
        *(float2*)(part + (((size_t)ch * B_SZ + b) * N_HEADS + h) * D_MODEL + dh * 512 + 2 * t) = acc[h];
}

// ---------------- kernel 5: cc[b, h*64+j] = sum_d vt[b,h,d]*Wv[d,h*64+j] + bv ----------------
// grid 1024 = (b,h), block 64 (1 wave); vt = sum of 8 partials, staged in LDS
__global__ __launch_bounds__(64) void k_cc(const float* __restrict__ part,
                                           const float* __restrict__ Wv,
                                           const float* __restrict__ bv,
                                           float* __restrict__ cc) {
    int b = blockIdx.x >> 4, h = blockIdx.x & 15;
    int lane = threadIdx.x;
    __shared__ float vt[D_MODEL];
#pragma unroll
    for (int p = 0; p < 4; ++p) {
        int i4 = lane + 64 * p;
        float4 s = make_float4(0.f, 0.f, 0.f, 0.f);
#pragma unroll
        for (int ch = 0; ch < 8; ++ch) {
            float4 x = *(const float4*)(part + (((size_t)ch * B_SZ + b) * N_HEADS + h) * D_MODEL + 4 * i4);
            s.x += x.x; s.y += x.y; s.z += x.z; s.w += x.w;
        }
        *(float4*)(vt + 4 * i4) = s;
    }
    __syncthreads();
    const float* w = Wv + h * D_K + lane;
    float acc = 0.f;
#pragma unroll 8
    for (int d = 0; d < D_MODEL; ++d) acc = fmaf(vt[d], w[(size_t)d * D_MODEL], acc);
    cc[(size_t)b * D_MODEL + h * D_K + lane] = acc + bv[h * D_K + lane];
}

// ---------------- kernel 6: out[b,n] = relu(cc[b,:] @ Wo[:,n] + bo[n]) ----------------
// grid 256 = (64 b x 4 n-chunks), block 256; cc row via uniform scalar loads
__global__ __launch_bounds__(256) void k_out(const float* __restrict__ cc,
                                             const float* __restrict__ Wo,
                                             const float* __restrict__ bo,
                                             float* __restrict__ out) {
    int b = blockIdx.x >> 2, nc = blockIdx.x & 3;
    int t = threadIdx.x;
    int n = nc * 256 + t;
    const float* w = Wo + n;
    const float* cb = cc + (size_t)b * D_MODEL;  // uniform -> s_load
    float acc = 0.f;
#pragma unroll 8
    for (int m = 0; m < D_MODEL; ++m) acc = fmaf(cb[m], w[(size_t)m * D_MODEL], acc);
    float r = acc + bo[n];
    out[(size_t)b * D_MODEL + n] = r > 0.f ? r : 0.f;
}

extern "C" void kernel_launch(void* const* d_in, const int* in_sizes, int n_in,
                              void* d_out, int out_size, void* d_ws, size_t ws_size,
                              hipStream_t stream) {
    const float* q  = (const float*)d_in[0];
    const float* k  = (const float*)d_in[1];
    const float* v  = (const float*)d_in[2];
    const float* Wq = (const float*)d_in[3];
    const float* bq = (const float*)d_in[4];
    const float* Wk = (const float*)d_in[5];
    // d_in[6] = bk: unused — softmax is shift-invariant, qh.bk is constant per (b,h) row
    const float* Wv = (const float*)d_in[7];
    const float* bv = (const float*)d_in[8];
    const float* Wo = (const float*)d_in[9];
    const float* bo = (const float*)d_in[10];
    float* out = (float*)d_out;

    float* ws = (float*)d_ws;
    float* qh   = ws;                       // 65536
    float* qt   = qh + 65536;               // 1048576
    float* sc   = qt + 1048576;             // 2097152
    float* part = sc + 2097152;             // 8388608
    float* cc   = part + 8388608;           // 65536   (total ~46.7 MB)

    k_qh<<<256, 256, 0, stream>>>(q, Wq, bq, qh);
    k_qtil<<<1024, 256, 0, stream>>>(qh, Wk, qt);
    k_scores<<<1024, 256, 0, stream>>>(k, qt, sc);
    k_softmax<<<1024, 256, 0, stream>>>(sc);
    k_av<<<1024, 256, 0, stream>>>(v, sc, part);
    k_cc<<<1024, 64, 0, stream>>>(part, Wv, bv, cc);
    k_out<<<256, 256, 0, stream>>>(cc, Wo, bo, out);
}